// Round 1
// 526.567 us; speedup vs baseline: 1.0409x; 1.0409x over previous
//
#include <hip/hip_runtime.h>
#include <cstdint>

// ---------------------------------------------------------------------------
// BotRGCN round 8: hide the CSR-build atomics.
//  - k_rank's 1.6M returning atomics (71 us standalone, atomic-service bound
//    at ~27 cy/op/CU) are fused into k_pre: issue at thread start, feature
//    embed runs under the drain, ranks collected at the end (k_pre has no
//    barriers, so no vmcnt(0)-at-barrier coupling).
//  - k_scatter's fire-and-forget random stores are fused into the embed
//    k_mgemm (same 782x2048 edge chunking); scans move before the embed GEMM.
// GEMM / gather structure unchanged from round 7.
// ---------------------------------------------------------------------------

typedef short bf16x8 __attribute__((ext_vector_type(8)));
typedef float f32x4  __attribute__((ext_vector_type(4)));

__device__ __forceinline__ unsigned short f2bf(float f) {
    unsigned int u = __builtin_bit_cast(unsigned int, f);
    u += 0x7fff + ((u >> 16) & 1);          // RNE
    return (unsigned short)(u >> 16);
}
__device__ __forceinline__ float bf2f(unsigned short h) {
    unsigned int u = ((unsigned int)h) << 16;
    return __builtin_bit_cast(float, u);
}
__device__ __forceinline__ float lo16f(unsigned int u) {
    return __builtin_bit_cast(float, u << 16);
}
__device__ __forceinline__ float hi16f(unsigned int u) {
    return __builtin_bit_cast(float, u & 0xffff0000u);
}

__device__ __forceinline__ void gload_lds16(const void* g, void* l) {
    __builtin_amdgcn_global_load_lds(
        (const __attribute__((address_space(1))) void*)g,
        (__attribute__((address_space(3))) void*)l, 16, 0, 0);
}

// ---- feature pre-embed into hi/lo planes + fused edge rank atomics ----
// Edge work: block b owns edges [b*2048, b*2048+2048), 8 per thread.
// Atomics issue before the feature compute (overlap), ranks stored after.
__global__ __launch_bounds__(256) void k_pre(
    const float* __restrict__ x,
    const float* __restrict__ Wnum, const float* __restrict__ bnum,
    const float* __restrict__ Wcat, const float* __restrict__ bcat,
    unsigned short* __restrict__ hi, unsigned short* __restrict__ lo, int N,
    const int* __restrict__ ei, const int* __restrict__ et,
    int* __restrict__ deg, int* __restrict__ rank, int E)
{
    const int tid = threadIdx.x;
    const int ebase = blockIdx.x * 2048 + tid;
    int r[8];
    #pragma unroll
    for (int j = 0; j < 8; ++j) {
        int e = ebase + j * 256;
        if (e < E) r[j] = atomicAdd(&deg[et[e] * N + ei[E + e]], 1);
    }

    int gid = blockIdx.x * 256 + tid;
    if (gid < N * 128) {
        int n = gid >> 7, k = gid & 127;
        const float* xr = x + n * 8;
        float acc;
        if (k < 64) {
            acc = bnum[k];
            #pragma unroll
            for (int p = 0; p < 5; ++p) acc += xr[p] * Wnum[p * 64 + k];
        } else {
            int kk = k - 64;
            acc = bcat[kk];
            #pragma unroll
            for (int p = 0; p < 3; ++p) acc += xr[5 + p] * Wcat[p * 64 + kk];
        }
        float v = acc >= 0.f ? acc : 0.01f * acc;
        unsigned short h = f2bf(v);
        hi[gid] = h;
        lo[gid] = f2bf(v - bf2f(h));
    }

    #pragma unroll
    for (int j = 0; j < 8; ++j) {
        int e = ebase + j * 256;
        if (e < E) rank[e] = r[j];
    }
}

// ---- weight split+transpose ----
struct WArgs {
    const float* W[8];
    unsigned short* hi[8];
    unsigned short* lo[8];
};
__global__ __launch_bounds__(256) void k_wsplit(WArgs a)
{
    int part = blockIdx.y;
    int idx = blockIdx.x * 256 + threadIdx.x;
    int n = idx >> 7, k = idx & 127;
    float v = a.W[part][(size_t)k * 128 + n];
    unsigned short h = f2bf(v);
    a.hi[part][(size_t)n * 128 + k] = h;
    a.lo[part][(size_t)n * 128 + k] = f2bf(v - bf2f(h));
}

__global__ __launch_bounds__(256) void k_scan1(
    const int* __restrict__ deg, int* __restrict__ off,
    int* __restrict__ bsum, int n)
{
    __shared__ int s[256];
    int t = threadIdx.x;
    int i = blockIdx.x * 256 + t;
    int v = (i < n) ? deg[i] : 0;
    s[t] = v;
    __syncthreads();
    #pragma unroll
    for (int d = 1; d < 256; d <<= 1) {
        int add = (t >= d) ? s[t - d] : 0;
        __syncthreads();
        s[t] += add;
        __syncthreads();
    }
    if (i < n) off[i] = s[t] - v;
    if (t == 255) bsum[blockIdx.x] = s[255];
}

__global__ __launch_bounds__(1024) void k_scan2(int* __restrict__ bsum, int nb)
{
    __shared__ int s[1024];
    int t = threadIdx.x;
    int v = (t < nb) ? bsum[t] : 0;
    s[t] = v;
    __syncthreads();
    #pragma unroll
    for (int d = 1; d < 1024; d <<= 1) {
        int add = (t >= d) ? s[t - d] : 0;
        __syncthreads();
        s[t] += add;
        __syncthreads();
    }
    if (t < nb) bsum[t] = s[t] - v;
}

__global__ __launch_bounds__(256) void k_scan3(
    int* __restrict__ off, const int* __restrict__ bsum, int n)
{
    int i = blockIdx.x * 256 + threadIdx.x;
    if (i < n) off[i] += bsum[blockIdx.x];
}

// ---- CSR scatter tail (only launched if the fused GEMM grid can't cover E)
__global__ __launch_bounds__(256) void k_scatter(
    const int* __restrict__ ei, const int* __restrict__ et,
    const int* __restrict__ off, const int* __restrict__ rank,
    int* __restrict__ esrc, int E, int N, int e0)
{
    int base = e0 + blockIdx.x * 2048 + threadIdx.x;
    #pragma unroll
    for (int j = 0; j < 8; ++j) {
        int e = base + j * 256;
        if (e < E) {
            int seg = et[e] * N + ei[E + e];
            esrc[off[seg] + rank[e]] = ei[e];
        }
    }
}

// ---- mean aggregation, bf16 hi plane, quarter-wave rows ----
__global__ __launch_bounds__(256) void k_gather(
    const unsigned short* __restrict__ h_hi,
    const int* __restrict__ esrc,
    const int* __restrict__ off, const int* __restrict__ deg,
    unsigned short* __restrict__ a_hi, int nseg)
{
    int i = blockIdx.x * 8 + (threadIdx.x >> 5);
    if (i >= nseg) return;
    int l32 = threadIdx.x & 31;
    int q = l32 >> 4;
    int l16 = l32 & 15;
    int cnt = deg[i], st = off[i];
    const uint4* hp = (const uint4*)h_hi;
    float a0 = 0.f, a1 = 0.f, a2 = 0.f, a3 = 0.f;
    float a4 = 0.f, a5 = 0.f, a6 = 0.f, a7 = 0.f;
    int e = q;
    for (; e + 6 < cnt; e += 8) {
        int i0 = esrc[st + e + 0];
        int i1 = esrc[st + e + 2];
        int i2 = esrc[st + e + 4];
        int i3 = esrc[st + e + 6];
        uint4 u0 = hp[(size_t)i0 * 16 + l16];
        uint4 u1 = hp[(size_t)i1 * 16 + l16];
        uint4 u2 = hp[(size_t)i2 * 16 + l16];
        uint4 u3 = hp[(size_t)i3 * 16 + l16];
        a0 += lo16f(u0.x); a1 += hi16f(u0.x); a2 += lo16f(u0.y); a3 += hi16f(u0.y);
        a4 += lo16f(u0.z); a5 += hi16f(u0.z); a6 += lo16f(u0.w); a7 += hi16f(u0.w);
        a0 += lo16f(u1.x); a1 += hi16f(u1.x); a2 += lo16f(u1.y); a3 += hi16f(u1.y);
        a4 += lo16f(u1.z); a5 += hi16f(u1.z); a6 += lo16f(u1.w); a7 += hi16f(u1.w);
        a0 += lo16f(u2.x); a1 += hi16f(u2.x); a2 += lo16f(u2.y); a3 += hi16f(u2.y);
        a4 += lo16f(u2.z); a5 += hi16f(u2.z); a6 += lo16f(u2.w); a7 += hi16f(u2.w);
        a0 += lo16f(u3.x); a1 += hi16f(u3.x); a2 += lo16f(u3.y); a3 += hi16f(u3.y);
        a4 += lo16f(u3.z); a5 += hi16f(u3.z); a6 += lo16f(u3.w); a7 += hi16f(u3.w);
    }
    for (; e < cnt; e += 2) {
        uint4 u = hp[(size_t)esrc[st + e] * 16 + l16];
        a0 += lo16f(u.x); a1 += hi16f(u.x); a2 += lo16f(u.y); a3 += hi16f(u.y);
        a4 += lo16f(u.z); a5 += hi16f(u.z); a6 += lo16f(u.w); a7 += hi16f(u.w);
    }
    a0 += __shfl_xor(a0, 16, 64);
    a1 += __shfl_xor(a1, 16, 64);
    a2 += __shfl_xor(a2, 16, 64);
    a3 += __shfl_xor(a3, 16, 64);
    a4 += __shfl_xor(a4, 16, 64);
    a5 += __shfl_xor(a5, 16, 64);
    a6 += __shfl_xor(a6, 16, 64);
    a7 += __shfl_xor(a7, 16, 64);
    if (q == 0) {
        float inv = 1.0f / (float)(cnt > 1 ? cnt : 1);
        uint4 o;
        o.x = (unsigned int)f2bf(a0 * inv) | ((unsigned int)f2bf(a1 * inv) << 16);
        o.y = (unsigned int)f2bf(a2 * inv) | ((unsigned int)f2bf(a3 * inv) << 16);
        o.z = (unsigned int)f2bf(a4 * inv) | ((unsigned int)f2bf(a5 * inv) << 16);
        o.w = (unsigned int)f2bf(a6 * inv) | ((unsigned int)f2bf(a7 * inv) << 16);
        ((uint4*)a_hi)[(size_t)i * 16 + l16] = o;
    }
}

// ---- pipelined split-bf16 MFMA GEMM (+ optional fused CSR scatter) ----
struct GArgs {
    const unsigned short* A_hi[3];
    const unsigned short* A_lo[3];
    const unsigned short* B_hi[3];   // transposed [n][k]
    const unsigned short* B_lo[3];
    int alo[3];
    int blo[3];
    const float* bias;
    const float* prelu;
    float* Cf;                       // if non-null: fp32 output
    unsigned short* C_hi;
    unsigned short* C_lo;
    int M;
    int P;
    // fused CSR scatter (embed call only); s_esrc == nullptr -> skip
    const int* s_ei;
    const int* s_et;
    const int* s_off;
    const int* s_rank;
    int* s_esrc;
    int s_E;
    int s_N;
};

__global__ __launch_bounds__(256) void k_mgemm(GArgs g)
{
    __shared__ unsigned short lds[2][32 * 512];   // 2 x 32 KB
    const int t = threadIdx.x;
    const int w = t >> 6, lane = t & 63;
    const int laneL = lane & 15, laneH = lane >> 4;
    const int wi = w >> 1, wj = w & 1;
    const int m0 = blockIdx.x * 128;
    const int Mm1 = g.M - 1;
    const int S = g.P * 4;

    // fused CSR scatter: fire-and-forget random stores drain under the GEMM
    if (g.s_esrc) {
        int ebase = blockIdx.x * 2048 + t;
        #pragma unroll
        for (int j = 0; j < 8; ++j) {
            int e = ebase + j * 256;
            if (e < g.s_E) {
                int seg = g.s_et[e] * g.s_N + g.s_ei[g.s_E + e];
                g.s_esrc[g.s_off[seg] + g.s_rank[e]] = g.s_ei[e];
            }
        }
    }

    f32x4 acc[4][4];
    #pragma unroll
    for (int a = 0; a < 4; ++a)
        #pragma unroll
        for (int b = 0; b < 4; ++b)
            acc[a][b] = (f32x4){0.f, 0.f, 0.f, 0.f};

    // stage step s into buffer buf: 32 chunks (tile slot*8 + j), round-robin by wave
    auto stage = [&](int s, unsigned short* buf) {
        int p = s >> 2, koff = (s & 3) * 32;
        const unsigned short* tp[4];
        tp[0] = g.A_hi[p];
        tp[1] = g.alo[p] ? g.A_lo[p] : nullptr;
        tp[2] = g.B_hi[p];
        tp[3] = g.blo[p] ? g.B_lo[p] : nullptr;
        #pragma unroll
        for (int c = 0; c < 8; ++c) {
            int chunk = w + c * 4;            // 0..31
            int slot = chunk >> 3, j = chunk & 7;
            const unsigned short* plane = tp[slot];
            if (!plane) continue;
            int rc = j * 16 + laneL;
            int row = (slot < 2) ? (m0 + rc <= Mm1 ? m0 + rc : Mm1) : rc;
            const unsigned short* gp = plane + (size_t)row * 128 + koff + laneH * 8;
            gload_lds16(gp, &buf[(slot * 8 + j) * 512]);
        }
    };

    stage(0, lds[0]);
    for (int s = 0; s < S; ++s) {
        unsigned short* cur = lds[s & 1];
        unsigned short* nxt = lds[(s & 1) ^ 1];
        __syncthreads();                      // drains stage(s); frees nxt
        if (s + 1 < S) stage(s + 1, nxt);     // overlaps with compute below
        int p = s >> 2;
        const bool hasAlo = g.alo[p] != 0;
        const bool hasBlo = g.blo[p] != 0;
        const bf16x8* fr = (const bf16x8*)cur;
        bf16x8 ah[4], al[4], bh[4], bl[4];
        #pragma unroll
        for (int mi = 0; mi < 4; ++mi)
            ah[mi] = fr[(0 + wi * 4 + mi) * 64 + lane];
        if (hasAlo) {
            #pragma unroll
            for (int mi = 0; mi < 4; ++mi)
                al[mi] = fr[(8 + wi * 4 + mi) * 64 + lane];
        }
        #pragma unroll
        for (int nj = 0; nj < 4; ++nj)
            bh[nj] = fr[(16 + wj * 4 + nj) * 64 + lane];
        if (hasBlo) {
            #pragma unroll
            for (int nj = 0; nj < 4; ++nj)
                bl[nj] = fr[(24 + wj * 4 + nj) * 64 + lane];
        }
        #pragma unroll
        for (int mi = 0; mi < 4; ++mi)
            #pragma unroll
            for (int nj = 0; nj < 4; ++nj) {
                acc[mi][nj] = __builtin_amdgcn_mfma_f32_16x16x32_bf16(
                    ah[mi], bh[nj], acc[mi][nj], 0, 0, 0);
                if (hasBlo)
                    acc[mi][nj] = __builtin_amdgcn_mfma_f32_16x16x32_bf16(
                        ah[mi], bl[nj], acc[mi][nj], 0, 0, 0);
                if (hasAlo)
                    acc[mi][nj] = __builtin_amdgcn_mfma_f32_16x16x32_bf16(
                        al[mi], bh[nj], acc[mi][nj], 0, 0, 0);
            }
    }

    // ---- epilogue: acc -> LDS (C layout) -> coalesced stores ----
    const bool hasPrelu = (g.prelu != nullptr);
    float bv[4], av[4];
    #pragma unroll
    for (int nj = 0; nj < 4; ++nj) {
        int col = wj * 64 + nj * 16 + laneL;
        bv[nj] = g.bias[col];
        av[nj] = hasPrelu ? g.prelu[col] : 0.f;
    }

    if (g.Cf) {
        // fp32 output: 128x128 f32 = 64 KB (both buffers)
        float* lf = (float*)&lds[0][0];
        __syncthreads();
        #pragma unroll
        for (int nj = 0; nj < 4; ++nj) {
            int col = wj * 64 + nj * 16 + laneL;
            #pragma unroll
            for (int mi = 0; mi < 4; ++mi)
                #pragma unroll
                for (int r = 0; r < 4; ++r) {
                    int row = wi * 64 + mi * 16 + laneH * 4 + r;
                    float v = acc[mi][nj][r] + bv[nj];
                    lf[row * 128 + col] = v;
                }
        }
        __syncthreads();
        const uint4* lsrc = (const uint4*)lf;
        #pragma unroll
        for (int it = 0; it < 16; ++it) {
            int idx = it * 256 + t;          // 4096 uint4
            int row = idx >> 5, c = idx & 31;
            int m = m0 + row;
            if (m < g.M)
                ((uint4*)(g.Cf + (size_t)m * 128))[c] = lsrc[idx];
        }
    } else {
        unsigned short* lp = &lds[0][0];     // 128x128 ushort = 32 KB
        // hi pass
        __syncthreads();
        #pragma unroll
        for (int nj = 0; nj < 4; ++nj) {
            int col = wj * 64 + nj * 16 + laneL;
            #pragma unroll
            for (int mi = 0; mi < 4; ++mi)
                #pragma unroll
                for (int r = 0; r < 4; ++r) {
                    int row = wi * 64 + mi * 16 + laneH * 4 + r;
                    float v = acc[mi][nj][r] + bv[nj];
                    if (hasPrelu) v = v >= 0.f ? v : av[nj] * v;
                    lp[row * 128 + col] = f2bf(v);
                }
        }
        __syncthreads();
        {
            const uint4* lsrc = (const uint4*)lp;
            #pragma unroll
            for (int it = 0; it < 8; ++it) {
                int idx = it * 256 + t;      // 2048 uint4
                int row = idx >> 4, c = idx & 15;
                int m = m0 + row;
                if (m < g.M)
                    ((uint4*)(g.C_hi + (size_t)m * 128))[c] = lsrc[idx];
            }
        }
        // lo pass
        __syncthreads();
        #pragma unroll
        for (int nj = 0; nj < 4; ++nj) {
            int col = wj * 64 + nj * 16 + laneL;
            #pragma unroll
            for (int mi = 0; mi < 4; ++mi)
                #pragma unroll
                for (int r = 0; r < 4; ++r) {
                    int row = wi * 64 + mi * 16 + laneH * 4 + r;
                    float v = acc[mi][nj][r] + bv[nj];
                    if (hasPrelu) v = v >= 0.f ? v : av[nj] * v;
                    unsigned short h = f2bf(v);
                    lp[row * 128 + col] = f2bf(v - bf2f(h));
                }
        }
        __syncthreads();
        {
            const uint4* lsrc = (const uint4*)lp;
            #pragma unroll
            for (int it = 0; it < 8; ++it) {
                int idx = it * 256 + t;
                int row = idx >> 4, c = idx & 15;
                int m = m0 + row;
                if (m < g.M)
                    ((uint4*)(g.C_lo + (size_t)m * 128))[c] = lsrc[idx];
            }
        }
    }
}

extern "C" void kernel_launch(void* const* d_in, const int* in_sizes, int n_in,
                              void* d_out, int out_size, void* d_ws, size_t ws_size,
                              hipStream_t stream) {
    const float* x      = (const float*)d_in[0];
    const int*   ei     = (const int*)d_in[1];
    const int*   et     = (const int*)d_in[2];
    const float* Wnum   = (const float*)d_in[3];
    const float* bnum   = (const float*)d_in[4];
    const float* Wcat   = (const float*)d_in[5];
    const float* bcat   = (const float*)d_in[6];
    const float* Win    = (const float*)d_in[7];
    const float* bin    = (const float*)d_in[8];
    const float* pa     = (const float*)d_in[9];
    const float* Wrel1  = (const float*)d_in[10];
    const float* Wroot1 = (const float*)d_in[11];
    const float* brg1   = (const float*)d_in[12];
    const float* Wrel2  = (const float*)d_in[13];
    const float* Wroot2 = (const float*)d_in[14];
    const float* brg2   = (const float*)d_in[15];
    const float* Wcls   = (const float*)d_in[16];
    const float* bcls   = (const float*)d_in[17];
    float* out = (float*)d_out;

    const int N = in_sizes[0] / 8;
    const int E = in_sizes[1] / 2;
    const int nseg = 2 * N;
    const size_t NH = (size_t)N * 128;

    char* w = (char*)d_ws;
    unsigned short* h0_hi = (unsigned short*)w;  w += NH * 2;
    unsigned short* h0_lo = (unsigned short*)w;  w += NH * 2;
    unsigned short* agg_hi = (unsigned short*)w; w += 2 * NH * 2;
    int* deg  = (int*)w;  w += (size_t)nseg * 4;
    int* off  = (int*)w;  w += (size_t)nseg * 4;
    int* rank = (int*)w;  w += (size_t)E * 4;
    int* esrc = (int*)w;  w += (size_t)E * 4;
    int* bsum = (int*)w;  w += 1024 * 4;
    unsigned short* wplanes = (unsigned short*)w;  w += 8 * 2 * 16384 * 2;

    unsigned short* hp_hi = agg_hi;
    unsigned short* hp_lo = agg_hi + NH;
    unsigned short* h1_hi = (unsigned short*)d_out;
    unsigned short* h1_lo = h1_hi + NH;
    unsigned short* h2_hi = h0_hi;
    unsigned short* h2_lo = h0_lo;

    unsigned short* whi[8];
    unsigned short* wlo[8];
    for (int i = 0; i < 8; ++i) {
        whi[i] = wplanes + (size_t)i * 2 * 16384;
        wlo[i] = whi[i] + 16384;
    }

    hipMemsetAsync(deg, 0, (size_t)nseg * sizeof(int), stream);

    {
        WArgs a;
        a.W[0] = Win;   a.W[1] = Wroot1; a.W[2] = Wrel1; a.W[3] = Wrel1 + 16384;
        a.W[4] = Wroot2; a.W[5] = Wrel2; a.W[6] = Wrel2 + 16384; a.W[7] = Wcls;
        for (int i = 0; i < 8; ++i) { a.hi[i] = whi[i]; a.lo[i] = wlo[i]; }
        k_wsplit<<<dim3(64, 8), 256, 0, stream>>>(a);
    }

    const int nb = (nseg + 255) / 256;
    const int gm = (N + 127) / 128;
    const int gg = (nseg + 7) / 8;

    // fused pre-embed + rank (grid covers both the N*128 gids and E/2048 chunks)
    {
        int gA = (N * 128 + 255) / 256;
        int gB = (E + 2047) / 2048;
        int gpre = gA > gB ? gA : gB;
        k_pre<<<gpre, 256, 0, stream>>>(x, Wnum, bnum, Wcat, bcat,
                                        hp_hi, hp_lo, N, ei, et, deg, rank, E);
    }

    k_scan1<<<nb, 256, 0, stream>>>(deg, off, bsum, nseg);
    k_scan2<<<1, 1024, 0, stream>>>(bsum, nb);
    k_scan3<<<nb, 256, 0, stream>>>(off, bsum, nseg);

    // embed GEMM with fused CSR scatter
    {
        GArgs g = {};
        g.A_hi[0] = hp_hi; g.A_lo[0] = hp_lo; g.alo[0] = 1; g.blo[0] = 1;
        g.B_hi[0] = whi[0]; g.B_lo[0] = wlo[0];
        g.bias = bin; g.prelu = pa;
        g.Cf = nullptr; g.C_hi = h0_hi; g.C_lo = h0_lo;
        g.M = N; g.P = 1;
        g.s_ei = ei; g.s_et = et; g.s_off = off; g.s_rank = rank;
        g.s_esrc = esrc; g.s_E = E; g.s_N = N;
        k_mgemm<<<gm, 256, 0, stream>>>(g);
    }
    // tail guard: if the GEMM grid couldn't cover all edges, finish the scatter
    if ((long long)gm * 2048 < (long long)E) {
        int covered = gm * 2048;
        int gt = (E - covered + 2047) / 2048;
        k_scatter<<<gt, 256, 0, stream>>>(ei, et, off, rank, esrc, E, N, covered);
    }

    // layer 1
    k_gather<<<gg, 256, 0, stream>>>(h0_hi, esrc, off, deg, agg_hi, nseg);
    {
        GArgs g = {};
        g.A_hi[0] = h0_hi;       g.A_lo[0] = h0_lo;  g.alo[0] = 1; g.blo[0] = 1;
        g.A_hi[1] = agg_hi;      g.alo[1] = 0;       g.blo[1] = 0;
        g.A_hi[2] = agg_hi + NH; g.alo[2] = 0;       g.blo[2] = 0;
        g.B_hi[0] = whi[1]; g.B_lo[0] = wlo[1];
        g.B_hi[1] = whi[2]; g.B_lo[1] = wlo[2];
        g.B_hi[2] = whi[3]; g.B_lo[2] = wlo[3];
        g.bias = brg1; g.prelu = nullptr;
        g.Cf = nullptr; g.C_hi = h1_hi; g.C_lo = h1_lo;
        g.M = N; g.P = 3;
        k_mgemm<<<gm, 256, 0, stream>>>(g);
    }
    // layer 2
    k_gather<<<gg, 256, 0, stream>>>(h1_hi, esrc, off, deg, agg_hi, nseg);
    {
        GArgs g = {};
        g.A_hi[0] = h1_hi;       g.A_lo[0] = h1_lo;  g.alo[0] = 1; g.blo[0] = 1;
        g.A_hi[1] = agg_hi;      g.alo[1] = 0;       g.blo[1] = 0;
        g.A_hi[2] = agg_hi + NH; g.alo[2] = 0;       g.blo[2] = 0;
        g.B_hi[0] = whi[4]; g.B_lo[0] = wlo[4];
        g.B_hi[1] = whi[5]; g.B_lo[1] = wlo[5];
        g.B_hi[2] = whi[6]; g.B_lo[2] = wlo[6];
        g.bias = brg2; g.prelu = nullptr;
        g.Cf = nullptr; g.C_hi = h2_hi; g.C_lo = h2_lo;
        g.M = N; g.P = 3;
        k_mgemm<<<gm, 256, 0, stream>>>(g);
    }
    // classifier
    {
        GArgs g = {};
        g.A_hi[0] = h2_hi; g.A_lo[0] = h2_lo; g.alo[0] = 1; g.blo[0] = 1;
        g.B_hi[0] = whi[7]; g.B_lo[0] = wlo[7];
        g.bias = bcls; g.prelu = nullptr;
        g.Cf = out; g.C_hi = nullptr; g.C_lo = nullptr;
        g.M = N; g.P = 1;
        k_mgemm<<<gm, 256, 0, stream>>>(g);
    }
}